// Round 9
// baseline (316.764 us; speedup 1.0000x reference)
//
#include <hip/hip_runtime.h>
#include <hip/hip_bf16.h>
#include <math.h>

#define B 128
#define S 1024
#define H 768
#define NH 8
#define DH 96
#define FUSED 2312
#define FPAD 2432            // fused row stride, padded to 19*128
#define KSPLIT 19
#define KCHUNK 128
#define ASL 8                // aspq slices
#define NSL 8                // flash slices per sample
#define FCH 16               // rows per flash chunk
#define NB 8                 // batches per qu/mergectx block
#define SCALE 0.10206207261596575f  // 1/sqrt(96)
#define GELU_C 0.70710678118654752f

__device__ __forceinline__ float dot4(float4 a, float4 b) {
    return a.x * b.x + a.y * b.y + a.z * b.z + a.w * b.w;
}

// ---------------------------------------------------------------------------
// K1: asp_query partials. grid (B, ASL), 192 threads (float4 cols).
// ---------------------------------------------------------------------------
__global__ void aspq_part_kernel(const float* __restrict__ lh,
                                 const int* __restrict__ sep1,
                                 const int* __restrict__ sep2,
                                 float* __restrict__ aspp) {
    int b = blockIdx.x, z = blockIdx.y, t = threadIdx.x;
    int s1 = sep1[b], s2 = sep2[b];
    int lo, hi;
    if (s2 > s1 + 1) { lo = s1 + 1; hi = s2; } else { lo = 0; hi = 1; }
    const float* base = lh + ((size_t)b * S) * H + 4 * t;
    float4 a = {0.f, 0.f, 0.f, 0.f};
    for (int s = lo + z; s < hi; s += ASL) {
        float4 r = *(const float4*)(base + (size_t)s * H);
        a.x += r.x; a.y += r.y; a.z += r.z; a.w += r.w;
    }
    *(float4*)(aspp + (size_t)z * (B * H) + b * H + 4 * t) = a;
}

// ---------------------------------------------------------------------------
// K2: qu v2 — batch-grouped. grid (B/NB, NH), 256 threads.
// Per block: merge aspq partials for 8 batches; q[8][96] = aq @ wq_h^T + bq;
// U[8][768] = q @ wk_h. Weights staged in LDS tiles, read once per 8 batches.
// ---------------------------------------------------------------------------
__global__ __launch_bounds__(256) void qu_kernel(
        const float* __restrict__ aspp,
        const int* __restrict__ sep1,
        const int* __restrict__ sep2,
        const float* __restrict__ wq,
        const float* __restrict__ bq,
        const float* __restrict__ wk,
        float* __restrict__ aspq,
        float* __restrict__ U) {
    int g = blockIdx.x, h = blockIdx.y, t = threadIdx.x;
    int b0 = g * NB;
    __shared__ float aq[NB][772];     // padded: 772 % 32 = 4
    __shared__ float Wt[96][33];
    __shared__ float qS[NB][100];
    __shared__ float WkS[96][68];

    // merge aspq partials (and publish aspq once, from h==0 blocks)
    for (int i = t; i < NB * H; i += 256) {
        int b = i / H, c = i - b * H;
        int gb = b0 + b;
        int s1 = sep1[gb], s2 = sep2[gb];
        int n = (s2 > s1 + 1) ? (s2 - s1 - 1) : 1;
        float a = 0.f;
#pragma unroll
        for (int z = 0; z < ASL; ++z)
            a += aspp[(size_t)z * (B * H) + (size_t)gb * H + c];
        a /= (float)n;
        aq[b][c] = a;
        if (h == 0) aspq[(size_t)gb * H + c] = a;
    }
    __syncthreads();

    // q[8][96] = aq @ wq_h^T  (K = 768, tiles of 32)
    int tb = t & 7, tn = t >> 3;      // tb: batch, tn: 0..31
    float qacc[3] = {0.f, 0.f, 0.f};
    for (int k0 = 0; k0 < H; k0 += 32) {
#pragma unroll
        for (int j = 0; j < 3; ++j) {
            int e4 = t + 256 * j;                 // 0..767 float4 slots
            int r = e4 >> 3, c4 = (e4 & 7) * 4;   // 96 rows x 8 f4
            float4 w = *(const float4*)(wq + (size_t)(h * DH + r) * H + k0 + c4);
            Wt[r][c4] = w.x; Wt[r][c4 + 1] = w.y;
            Wt[r][c4 + 2] = w.z; Wt[r][c4 + 3] = w.w;
        }
        __syncthreads();
#pragma unroll
        for (int kk = 0; kk < 32; ++kk) {
            float av = aq[tb][k0 + kk];
#pragma unroll
            for (int j = 0; j < 3; ++j)
                qacc[j] += av * Wt[tn + 32 * j][kk];
        }
        __syncthreads();
    }
#pragma unroll
    for (int j = 0; j < 3; ++j)
        qS[tb][tn + 32 * j] = qacc[j] + bq[h * DH + tn + 32 * j];
    __syncthreads();

    // U[8][768] = qS @ wk_h  (K = 96, c-tiles of 64)
    for (int c0 = 0; c0 < H; c0 += 64) {
#pragma unroll
        for (int j = 0; j < 6; ++j) {
            int e4 = t + 256 * j;                  // 0..1535: 96 rows x 16 f4
            int r = e4 >> 4, c4 = (e4 & 15) * 4;
            float4 w = *(const float4*)(wk + (size_t)(h * DH + r) * H + c0 + c4);
            WkS[r][c4] = w.x; WkS[r][c4 + 1] = w.y;
            WkS[r][c4 + 2] = w.z; WkS[r][c4 + 3] = w.w;
        }
        __syncthreads();
#pragma unroll
        for (int jj = 0; jj < 2; ++jj) {
            int cl = tn + 32 * jj;
            float a = 0.f;
#pragma unroll
            for (int d = 0; d < 96; ++d)
                a += qS[tb][d] * WkS[d][cl];
            U[((size_t)(b0 + tb) * NH + h) * H + c0 + cl] = a;
        }
        __syncthreads();
    }
}

// ---------------------------------------------------------------------------
// K3: flash — wave-per-head online softmax + weighted V-sum, one lh pass.
// grid (B, NSL), 512 threads (8 waves). Slice z owns rows tlo+z+NSL*j.
// ---------------------------------------------------------------------------
__global__ __launch_bounds__(512) void flash_kernel(
        const float* __restrict__ lhg,
        const float* __restrict__ U,
        const int* __restrict__ sep1,
        float* __restrict__ Op,     // [NSL][B][NH][H]
        float* __restrict__ mlb) {  // [NSL][B][NH][2]
    int b = blockIdx.x, z = blockIdx.y, t = threadIdx.x;
    int wave = t >> 6, lane = t & 63;
    int s1 = sep1[b];
    int tlo = (s1 > 1) ? 1 : 0;
    int thi = (s1 > 1) ? s1 : 1;
    int span = thi - tlo;
    int nrows = (span > z) ? ((span - z - 1) / NSL + 1) : 0;

    __shared__ float lhs[FCH][H];   // 48 KB

    const float4* Uh = (const float4*)(U + ((size_t)b * NH + wave) * H);
    float4 u0 = Uh[lane], u1 = Uh[lane + 64], u2 = Uh[lane + 128];
    float4 O0 = {0.f, 0.f, 0.f, 0.f}, O1 = O0, O2 = O0;
    float m = -1e30f, l = 0.f;

    int rid = t >> 5;        // 0..15 (staging row)
    int cid = t & 31;        // 0..31 (staging col group)

    for (int j0 = 0; j0 < nrows; j0 += FCH) {
        int nv = min(FCH, nrows - j0);
        if (rid < nv) {
            int sg = tlo + z + NSL * (j0 + rid);
            const float4* row = (const float4*)(lhg + ((size_t)b * S + sg) * H);
            float4* dst = (float4*)lhs[rid];
#pragma unroll
            for (int k = 0; k < 6; ++k) dst[cid + 32 * k] = row[cid + 32 * k];
        }
        __syncthreads();
        for (int r = 0; r < nv; ++r) {
            const float4* xr = (const float4*)lhs[r];
            float4 x0 = xr[lane], x1 = xr[lane + 64], x2 = xr[lane + 128];
            float s = dot4(u0, x0) + dot4(u1, x1) + dot4(u2, x2);
            for (int off = 32; off; off >>= 1) s += __shfl_xor(s, off);
            s *= SCALE;
            if (s <= m) {            // common path: no rescale
                float p = __expf(s - m);
                l += p;
                O0.x += p * x0.x; O0.y += p * x0.y; O0.z += p * x0.z; O0.w += p * x0.w;
                O1.x += p * x1.x; O1.y += p * x1.y; O1.z += p * x1.z; O1.w += p * x1.w;
                O2.x += p * x2.x; O2.y += p * x2.y; O2.z += p * x2.z; O2.w += p * x2.w;
            } else {                 // max moved: rescale, p == 1
                float c = __expf(m - s);
                m = s;
                l = l * c + 1.0f;
                O0.x = O0.x * c + x0.x; O0.y = O0.y * c + x0.y;
                O0.z = O0.z * c + x0.z; O0.w = O0.w * c + x0.w;
                O1.x = O1.x * c + x1.x; O1.y = O1.y * c + x1.y;
                O1.z = O1.z * c + x1.z; O1.w = O1.w * c + x1.w;
                O2.x = O2.x * c + x2.x; O2.y = O2.y * c + x2.y;
                O2.z = O2.z * c + x2.z; O2.w = O2.w * c + x2.w;
            }
        }
        __syncthreads();
    }
    float4* Ob = (float4*)(Op + (((size_t)z * B + b) * NH + wave) * H);
    Ob[lane] = O0; Ob[lane + 64] = O1; Ob[lane + 128] = O2;
    if (lane == 0) {
        float* ml = mlb + ((size_t)z * B + b) * NH * 2;
        ml[2 * wave]     = m;
        ml[2 * wave + 1] = l;
    }
}

// ---------------------------------------------------------------------------
// K4: mergectx v2 — batch-grouped. grid (B/NB, NH), 256 threads.
// Merge flash slices -> wsum[8][768] (LDS); ctx[8][96] = wv_h @ wsum + bv.
// ---------------------------------------------------------------------------
__global__ __launch_bounds__(256) void mergectx_kernel(
        const float* __restrict__ Op,
        const float* __restrict__ mlb,
        const float* __restrict__ wv,
        const float* __restrict__ bv,
        float* __restrict__ ctx) {
    int g = blockIdx.x, h = blockIdx.y, t = threadIdx.x;
    int b0 = g * NB;
    __shared__ float wsum[NB][772];
    __shared__ float Wt[96][33];
    __shared__ float wzS[NB][NSL];
    __shared__ float LiS[NB];

    if (t < NB) {
        int gb = b0 + t;
        float M = -1e30f;
#pragma unroll
        for (int z = 0; z < NSL; ++z)
            M = fmaxf(M, mlb[(((size_t)z * B + gb) * NH + h) * 2]);
        float L = 0.f;
#pragma unroll
        for (int z = 0; z < NSL; ++z) {
            const float* ml = mlb + (((size_t)z * B + gb) * NH + h) * 2;
            float e = __expf(ml[0] - M);
            wzS[t][z] = e;
            L += e * ml[1];
        }
        LiS[t] = 1.0f / L;
    }
    __syncthreads();
    for (int i = t; i < NB * H; i += 256) {
        int b = i / H, c = i - b * H;
        float a = 0.f;
#pragma unroll
        for (int z = 0; z < NSL; ++z)
            a += wzS[b][z] * Op[(((size_t)z * B + b0 + b) * NH + h) * H + c];
        wsum[b][c] = a * LiS[b];
    }
    __syncthreads();

    // ctx[8][96] = wsum @ wv_h^T + bv  (K = 768, tiles of 32)
    int tb = t & 7, tn = t >> 3;
    float acc[3] = {0.f, 0.f, 0.f};
    for (int k0 = 0; k0 < H; k0 += 32) {
#pragma unroll
        for (int j = 0; j < 3; ++j) {
            int e4 = t + 256 * j;
            int r = e4 >> 3, c4 = (e4 & 7) * 4;
            float4 w = *(const float4*)(wv + (size_t)(h * DH + r) * H + k0 + c4);
            Wt[r][c4] = w.x; Wt[r][c4 + 1] = w.y;
            Wt[r][c4 + 2] = w.z; Wt[r][c4 + 3] = w.w;
        }
        __syncthreads();
#pragma unroll
        for (int kk = 0; kk < 32; ++kk) {
            float av = wsum[tb][k0 + kk];
#pragma unroll
            for (int j = 0; j < 3; ++j)
                acc[j] += av * Wt[tn + 32 * j][kk];
        }
        __syncthreads();
    }
#pragma unroll
    for (int j = 0; j < 3; ++j) {
        int d = tn + 32 * j;
        ctx[(size_t)(b0 + tb) * H + h * DH + d] = acc[j] + bv[h * DH + d];
    }
}

// ---------------------------------------------------------------------------
// Generic small fp32 GEMM, float4 loads, 32x32 tiles, z split-K.
// ---------------------------------------------------------------------------
template <int TAG, bool KCL>
__global__ void gemm_kernel(const float* __restrict__ A, int lda, int a_bs,
                            const float* __restrict__ W, int ldw, int w_bs,
                            float* __restrict__ C, int ldc, int c_bs,
                            int M, int N, int K, int kclamp) {
    A += (size_t)blockIdx.z * a_bs;
    W += (size_t)blockIdx.z * w_bs;
    C += (size_t)blockIdx.z * c_bs;
    int kcl = KCL ? (kclamp - (int)blockIdx.z * w_bs) : 0;
    int n0 = blockIdx.x * 32, m0 = blockIdx.y * 32;
    __shared__ float As[32][33];
    __shared__ float Ws[32][33];
    int t = threadIdx.x;
    int tx = t & 31, ty = t >> 5;
    int lr = t >> 3, lc = (t & 7) * 4;
    float acc[4] = {0.f, 0.f, 0.f, 0.f};
    for (int k0 = 0; k0 < K; k0 += 32) {
        {
            float4 a = *(const float4*)(A + (size_t)(m0 + lr) * lda + k0 + lc);
            As[lr][lc] = a.x; As[lr][lc + 1] = a.y;
            As[lr][lc + 2] = a.z; As[lr][lc + 3] = a.w;
        }
        {
            int kk = k0 + lc;
            if (KCL) kk = min(kk, kcl);
            float4 w = *(const float4*)(W + (size_t)(n0 + lr) * ldw + kk);
            Ws[lr][lc] = w.x; Ws[lr][lc + 1] = w.y;
            Ws[lr][lc + 2] = w.z; Ws[lr][lc + 3] = w.w;
        }
        __syncthreads();
#pragma unroll
        for (int kk = 0; kk < 32; ++kk) {
            float wv = Ws[tx][kk];
#pragma unroll
            for (int i = 0; i < 4; ++i)
                acc[i] += As[ty + 8 * i][kk] * wv;
        }
        __syncthreads();
    }
    int n = n0 + tx;
#pragma unroll
    for (int i = 0; i < 4; ++i) {
        int m = m0 + ty + 8 * i;
        C[(size_t)m * ldc + n] = acc[i];
    }
}

// ---------------------------------------------------------------------------
// fuse: fused[b] = [lh[b,0,:], merge(crossp)+out_b, aspq, LN(aro)], zero-pad.
// ---------------------------------------------------------------------------
__global__ void fuse_kernel(const float* __restrict__ lh,
                            const float* __restrict__ crossp,
                            const float* __restrict__ out_b,
                            const float* __restrict__ aspq,
                            const float* __restrict__ aro_f,
                            const float* __restrict__ ln_g,
                            const float* __restrict__ ln_b,
                            float* __restrict__ fused) {
    int b = blockIdx.x, t = threadIdx.x;
    float* fb = fused + (size_t)b * FPAD;
    const float* lhb = lh + (size_t)b * S * H;
    for (int i = t; i < H; i += 256) {
        float cr = out_b[i];
#pragma unroll
        for (int z = 0; z < 6; ++z) cr += crossp[(size_t)z * (B * H) + b * H + i];
        fb[i]         = lhb[i];
        fb[H + i]     = cr;
        fb[2 * H + i] = aspq[b * H + i];
    }
    for (int i = t; i < FPAD - FUSED; i += 256) fb[FUSED + i] = 0.f;
    if (t < 8) {
        const float* af = aro_f + b * 8;
        float mu = 0.f;
#pragma unroll
        for (int j = 0; j < 8; ++j) mu += af[j];
        mu *= 0.125f;
        float var = 0.f;
#pragma unroll
        for (int j = 0; j < 8; ++j) { float d = af[j] - mu; var += d * d; }
        var *= 0.125f;
        fb[3 * H + t] = (af[t] - mu) * rsqrtf(var + 1e-5f) * ln_g[t] + ln_b[t];
    }
}

// ---------------------------------------------------------------------------
// mlp2: reduce hdn1 split-K partials + gelu; hdn2; all 8 head outputs.
// ---------------------------------------------------------------------------
__global__ void mlp2_kernel(const float* __restrict__ hdn1p,
                            const float* __restrict__ fusedb,
                            const float* __restrict__ va_b1,
                            const float* __restrict__ va_w2,
                            const float* __restrict__ va_b2,
                            const float* __restrict__ va_w3,
                            const float* __restrict__ va_b3,
                            const float* __restrict__ pol_w,
                            const float* __restrict__ pol_b,
                            const float* __restrict__ aro_w,
                            const float* __restrict__ aro_b,
                            float* __restrict__ out) {
    int b = blockIdx.x, t = threadIdx.x;
    __shared__ float hs[512];
    __shared__ float h2[128];
    for (int n = t; n < 512; n += 256) {
        float sacc = 0.f;
#pragma unroll
        for (int z = 0; z < KSPLIT; ++z)
            sacc += hdn1p[(size_t)z * (B * 512) + b * 512 + n];
        sacc += va_b1[n];
        hs[n] = 0.5f * sacc * (1.0f + erff(sacc * GELU_C));
    }
    __syncthreads();
    int wave = t >> 6, lane = t & 63;
    for (int i = 0; i < 32; ++i) {
        int n = wave * 32 + i;
        float a = 0.f;
#pragma unroll
        for (int j = 0; j < 8; ++j) {
            int k = lane + 64 * j;
            a += hs[k] * va_w2[(size_t)n * 512 + k];
        }
        for (int off = 32; off; off >>= 1) a += __shfl_xor(a, off);
        if (lane == 0) {
            float x = a + va_b2[n];
            h2[n] = 0.5f * x * (1.0f + erff(x * GELU_C));
        }
    }
    __syncthreads();
    const float* fb = fusedb + (size_t)b * FPAD;
    for (int oi = 0; oi < 2; ++oi) {
        int o = wave * 2 + oi;
        float acc = 0.f, bia;
        float* dst;
        if (o < 2) {
            for (int k = lane; k < 128; k += 64) acc += h2[k] * va_w3[o * 128 + k];
            bia = va_b3[o]; dst = out + b * 2 + o;
        } else if (o < 5) {
            int r = o - 2;
            for (int k = lane; k < FUSED; k += 64) acc += fb[k] * pol_w[(size_t)r * FUSED + k];
            bia = pol_b[r]; dst = out + 256 + b * 3 + r;
        } else {
            int r = o - 5;
            for (int k = lane; k < FUSED; k += 64) acc += fb[k] * aro_w[(size_t)r * FUSED + k];
            bia = aro_b[r]; dst = out + 640 + b * 3 + r;
        }
        for (int off = 32; off; off >>= 1) acc += __shfl_xor(acc, off);
        if (lane == 0) *dst = acc + bia;
    }
}

// ---------------------------------------------------------------------------
extern "C" void kernel_launch(void* const* d_in, const int* in_sizes, int n_in,
                              void* d_out, int out_size, void* d_ws, size_t ws_size,
                              hipStream_t stream) {
    const float* lh    = (const float*)d_in[0];
    const float* aro_f = (const float*)d_in[1];
    const int*   sep1  = (const int*)d_in[2];
    const int*   sep2  = (const int*)d_in[3];
    const float* in_w  = (const float*)d_in[4];
    const float* in_b  = (const float*)d_in[5];
    const float* out_w = (const float*)d_in[6];
    const float* out_b = (const float*)d_in[7];
    const float* ln_g  = (const float*)d_in[8];
    const float* ln_b  = (const float*)d_in[9];
    const float* va_w1 = (const float*)d_in[10];
    const float* va_b1 = (const float*)d_in[11];
    const float* va_w2 = (const float*)d_in[12];
    const float* va_b2 = (const float*)d_in[13];
    const float* va_w3 = (const float*)d_in[14];
    const float* va_b3 = (const float*)d_in[15];
    const float* pol_w = (const float*)d_in[16];
    const float* pol_b = (const float*)d_in[17];
    const float* aro_w = (const float*)d_in[18];
    const float* aro_b = (const float*)d_in[19];
    float* out = (float*)d_out;

    float* ws = (float*)d_ws;
    float* aspp   = ws;                              // ASL*B*H
    float* aspq   = aspp + ASL * B * H;              // B*H
    float* Ubuf   = aspq + B * H;                    // B*NH*H
    float* Opb    = Ubuf + B * NH * H;               // NSL*B*NH*H
    float* mlbuf  = Opb + (size_t)NSL * B * NH * H;  // NSL*B*NH*2
    float* ctx    = mlbuf + NSL * B * NH * 2;        // B*H
    float* crossp = ctx + B * H;                     // 6*B*H
    float* fusedb = crossp + 6 * B * H;              // B*FPAD
    float* hdn1p  = fusedb + B * FPAD;               // 19*B*512

    const float* wq = in_w;
    const float* wk = in_w + H * H;
    const float* wv = in_w + 2 * H * H;
    const float* bq = in_b;
    const float* bv = in_b + 2 * H;

    // 1) asp_query partials
    aspq_part_kernel<<<dim3(B, ASL), 192, 0, stream>>>(lh, sep1, sep2, aspp);
    // 2) qu v2 (batch-grouped): merge + q + U
    qu_kernel<<<dim3(B / NB, NH), 256, 0, stream>>>(aspp, sep1, sep2, wq, bq,
                                                    wk, aspq, Ubuf);
    // 3) flash (wave-per-head)
    flash_kernel<<<dim3(B, NSL), 512, 0, stream>>>(lh, Ubuf, sep1, Opb, mlbuf);
    // 4) mergectx v2 (batch-grouped)
    mergectx_kernel<<<dim3(B / NB, NH), 256, 0, stream>>>(Opb, mlbuf, wv, bv, ctx);
    // 5) cross partials = ctx @ out_w.T : split-K 6x128 (merged in fuse)
    gemm_kernel<3, false><<<dim3(24, 4, 6), 256, 0, stream>>>(
        ctx, H, KCHUNK, out_w, H, KCHUNK, crossp, H, B * H, B, H, KCHUNK, 0);
    // 6) fused assembly (+cross merge, +LN, +pad)
    fuse_kernel<<<B, 256, 0, stream>>>(lh, crossp, out_b, aspq, aro_f,
                                       ln_g, ln_b, fusedb);
    // 7) hdn1 split-K partials (19 x 128)
    gemm_kernel<4, true><<<dim3(16, 4, KSPLIT), 256, 0, stream>>>(
        fusedb, FPAD, KCHUNK, va_w1, FUSED, KCHUNK,
        hdn1p, 512, B * 512, B, 512, KCHUNK, FUSED - 4);
    // 8) mlp2: reduce+gelu + hdn2 + heads
    mlp2_kernel<<<B, 256, 0, stream>>>(hdn1p, fusedb, va_b1, va_w2, va_b2,
                                       va_w3, va_b3, pol_w, pol_b,
                                       aro_w, aro_b, out);
}

// Round 10
// 262.571 us; speedup vs baseline: 1.2064x; 1.2064x over previous
//
#include <hip/hip_runtime.h>
#include <hip/hip_bf16.h>
#include <math.h>

#define B 128
#define S 1024
#define H 768
#define NH 8
#define DH 96
#define FUSED 2312
#define KSPLIT 19
#define KCHUNK 128
#define NOUT 544             // 512 hdn1 + 3 pol + 3 aro + pad
#define ASL 8                // aspq slices
#define NSL 8                // flash slices per sample
#define FCH 16               // rows per flash chunk
#define SCALE 0.10206207261596575f  // 1/sqrt(96)
#define GELU_C 0.70710678118654752f

__device__ __forceinline__ float dot4(float4 a, float4 b) {
    return a.x * b.x + a.y * b.y + a.z * b.z + a.w * b.w;
}

__device__ __forceinline__ float gelu(float x) {
    return 0.5f * x * (1.0f + erff(x * GELU_C));
}

// ---------------------------------------------------------------------------
// K1: asp_query partials. grid (B, ASL), 192 threads (float4 cols).
// ---------------------------------------------------------------------------
__global__ void aspq_part_kernel(const float* __restrict__ lh,
                                 const int* __restrict__ sep1,
                                 const int* __restrict__ sep2,
                                 float* __restrict__ aspp) {
    int b = blockIdx.x, z = blockIdx.y, t = threadIdx.x;
    int s1 = sep1[b], s2 = sep2[b];
    int lo, hi;
    if (s2 > s1 + 1) { lo = s1 + 1; hi = s2; } else { lo = 0; hi = 1; }
    const float* base = lh + ((size_t)b * S) * H + 4 * t;
    float4 a = {0.f, 0.f, 0.f, 0.f};
    for (int s = lo + z; s < hi; s += ASL) {
        float4 r = *(const float4*)(base + (size_t)s * H);
        a.x += r.x; a.y += r.y; a.z += r.z; a.w += r.w;
    }
    *(float4*)(aspp + (size_t)z * (B * H) + b * H + 4 * t) = a;
}

// ---------------------------------------------------------------------------
// K2: qu (R7 form) — merge aspq partials; q_h = aspq @ wq_h.T + bq_h;
// U = q_h @ wk_h. grid (B, NH), 256 threads. h==0 blocks publish aspq.
// ---------------------------------------------------------------------------
__global__ void qu_kernel(const float* __restrict__ aspp,
                          const int* __restrict__ sep1,
                          const int* __restrict__ sep2,
                          const float* __restrict__ wq,
                          const float* __restrict__ bq,
                          const float* __restrict__ wk,
                          float* __restrict__ aspq,
                          float* __restrict__ U) {
    int b = blockIdx.x, h = blockIdx.y, t = threadIdx.x;
    int s1 = sep1[b], s2 = sep2[b];
    int lo, hi;
    if (s2 > s1 + 1) { lo = s1 + 1; hi = s2; } else { lo = 0; hi = 1; }
    float inv = 1.0f / (float)(hi - lo);
    __shared__ float aq[H];
    __shared__ float qh[DH];
    for (int c = t; c < H; c += 256) {
        float a = 0.f;
#pragma unroll
        for (int z = 0; z < ASL; ++z)
            a += aspp[(size_t)z * (B * H) + b * H + c];
        a *= inv;
        aq[c] = a;
        if (h == 0) aspq[b * H + c] = a;
    }
    __syncthreads();
    int wave = t >> 6, lane = t & 63;
#pragma unroll
    for (int i = 0; i < 24; ++i) {
        int d = wave * 24 + i;
        const float* wrow = wq + (size_t)(h * DH + d) * H;
        float a = 0.f;
#pragma unroll
        for (int j = 0; j < H / 64; ++j) a += wrow[lane + 64 * j] * aq[lane + 64 * j];
        for (int off = 32; off; off >>= 1) a += __shfl_xor(a, off);
        if (lane == 0) qh[d] = a + bq[h * DH + d];
    }
    __syncthreads();
    float u0 = 0.f, u1 = 0.f, u2 = 0.f;
    for (int d = 0; d < DH; ++d) {
        const float* wrow = wk + (size_t)(h * DH + d) * H;
        float qd = qh[d];
        u0 += qd * wrow[t];
        u1 += qd * wrow[t + 256];
        u2 += qd * wrow[t + 512];
    }
    float* Ub = U + ((size_t)b * NH + h) * H;
    Ub[t] = u0; Ub[t + 256] = u1; Ub[t + 512] = u2;
}

// ---------------------------------------------------------------------------
// K3: flash (R7 form) — wave-per-head online softmax + weighted V-sum.
// grid (B, NSL), 512 threads (8 waves).
// ---------------------------------------------------------------------------
__global__ __launch_bounds__(512) void flash_kernel(
        const float* __restrict__ lhg,
        const float* __restrict__ U,
        const int* __restrict__ sep1,
        float* __restrict__ Op,     // [NSL][B][NH][H]
        float* __restrict__ mlb) {  // [NSL][B][NH][2]
    int b = blockIdx.x, z = blockIdx.y, t = threadIdx.x;
    int wave = t >> 6, lane = t & 63;
    int s1 = sep1[b];
    int tlo = (s1 > 1) ? 1 : 0;
    int thi = (s1 > 1) ? s1 : 1;
    int span = thi - tlo;
    int nrows = (span > z) ? ((span - z - 1) / NSL + 1) : 0;

    __shared__ float lhs[FCH][H];   // 48 KB

    const float4* Uh = (const float4*)(U + ((size_t)b * NH + wave) * H);
    float4 u0 = Uh[lane], u1 = Uh[lane + 64], u2 = Uh[lane + 128];
    float4 O0 = {0.f, 0.f, 0.f, 0.f}, O1 = O0, O2 = O0;
    float m = -1e30f, l = 0.f;

    int rid = t >> 5;        // 0..15 (staging row)
    int cid = t & 31;        // 0..31 (staging col group)

    for (int j0 = 0; j0 < nrows; j0 += FCH) {
        int nv = min(FCH, nrows - j0);
        if (rid < nv) {
            int sg = tlo + z + NSL * (j0 + rid);
            const float4* row = (const float4*)(lhg + ((size_t)b * S + sg) * H);
            float4* dst = (float4*)lhs[rid];
#pragma unroll
            for (int k = 0; k < 6; ++k) dst[cid + 32 * k] = row[cid + 32 * k];
        }
        __syncthreads();
        for (int r = 0; r < nv; ++r) {
            const float4* xr = (const float4*)lhs[r];
            float4 x0 = xr[lane], x1 = xr[lane + 64], x2 = xr[lane + 128];
            float s = dot4(u0, x0) + dot4(u1, x1) + dot4(u2, x2);
            for (int off = 32; off; off >>= 1) s += __shfl_xor(s, off);
            s *= SCALE;
            if (s <= m) {            // common path: no rescale
                float p = __expf(s - m);
                l += p;
                O0.x += p * x0.x; O0.y += p * x0.y; O0.z += p * x0.z; O0.w += p * x0.w;
                O1.x += p * x1.x; O1.y += p * x1.y; O1.z += p * x1.z; O1.w += p * x1.w;
                O2.x += p * x2.x; O2.y += p * x2.y; O2.z += p * x2.z; O2.w += p * x2.w;
            } else {                 // max moved: rescale, p == 1
                float c = __expf(m - s);
                m = s;
                l = l * c + 1.0f;
                O0.x = O0.x * c + x0.x; O0.y = O0.y * c + x0.y;
                O0.z = O0.z * c + x0.z; O0.w = O0.w * c + x0.w;
                O1.x = O1.x * c + x1.x; O1.y = O1.y * c + x1.y;
                O1.z = O1.z * c + x1.z; O1.w = O1.w * c + x1.w;
                O2.x = O2.x * c + x2.x; O2.y = O2.y * c + x2.y;
                O2.z = O2.z * c + x2.z; O2.w = O2.w * c + x2.w;
            }
        }
        __syncthreads();
    }
    float4* Ob = (float4*)(Op + (((size_t)z * B + b) * NH + wave) * H);
    Ob[lane] = O0; Ob[lane + 64] = O1; Ob[lane + 128] = O2;
    if (lane == 0) {
        float* ml = mlb + ((size_t)z * B + b) * NH * 2;
        ml[2 * wave]     = m;
        ml[2 * wave + 1] = l;
    }
}

// ---------------------------------------------------------------------------
// K4: mergectx (R7 form + cross partial) — grid (B, NH), 256 threads.
//  phase1: merge flash slices -> wsum[768] (LDS)
//  phase2: ctx_h[96] = wv_h @ wsum + bv (LDS)
//  phase3: crossp[h][b][:] = out_w[:, h*96:+96] . ctx_h   (LDS-tiled out_w)
// ---------------------------------------------------------------------------
__global__ __launch_bounds__(256) void mergectx_kernel(
        const float* __restrict__ Op,
        const float* __restrict__ mlb,
        const float* __restrict__ wv,
        const float* __restrict__ bv,
        const float* __restrict__ out_w,
        float* __restrict__ crossp) {
    int b = blockIdx.x, h = blockIdx.y, t = threadIdx.x;
    __shared__ float wsum[H];
    __shared__ float ctxS[DH];
    __shared__ float Wt2[64][100];

    // phase 1
    float M = -1e30f;
#pragma unroll
    for (int z = 0; z < NSL; ++z)
        M = fmaxf(M, mlb[(((size_t)z * B + b) * NH + h) * 2]);
    float wz[NSL], L = 0.f;
#pragma unroll
    for (int z = 0; z < NSL; ++z) {
        const float* ml = mlb + (((size_t)z * B + b) * NH + h) * 2;
        float e = __expf(ml[0] - M);
        wz[z] = e;
        L += e * ml[1];
    }
    float Li = 1.0f / L;
    for (int c = t; c < H; c += 256) {
        float a = 0.f;
#pragma unroll
        for (int z = 0; z < NSL; ++z)
            a += wz[z] * Op[(((size_t)z * B + b) * NH + h) * H + c];
        wsum[c] = a * Li;
    }
    __syncthreads();

    // phase 2: ctx_h (4 waves x 24 outputs)
    int wave = t >> 6, lane = t & 63;
#pragma unroll
    for (int i = 0; i < 24; ++i) {
        int d = wave * 24 + i;
        const float* wrow = wv + (size_t)(h * DH + d) * H;
        float a = 0.f;
#pragma unroll
        for (int j = 0; j < H / 64; ++j) a += wrow[lane + 64 * j] * wsum[lane + 64 * j];
        for (int off = 32; off; off >>= 1) a += __shfl_xor(a, off);
        if (lane == 0) ctxS[d] = a + bv[h * DH + d];
    }
    __syncthreads();

    // phase 3: cross partial, 12 tiles of 64 outputs
    int r = t >> 2, sub = t & 3;
    for (int o0 = 0; o0 < H; o0 += 64) {
        for (int i = t; i < 64 * 24; i += 256) {
            int rr = i / 24, c4 = (i % 24) * 4;
            float4 w = *(const float4*)(out_w + (size_t)(o0 + rr) * H + h * DH + c4);
            Wt2[rr][c4] = w.x; Wt2[rr][c4 + 1] = w.y;
            Wt2[rr][c4 + 2] = w.z; Wt2[rr][c4 + 3] = w.w;
        }
        __syncthreads();
        float a = 0.f;
#pragma unroll
        for (int j = 0; j < 24; ++j) {
            int d = sub * 24 + j;
            a += Wt2[r][d] * ctxS[d];
        }
        a += __shfl_xor(a, 1);
        a += __shfl_xor(a, 2);
        if (sub == 0)
            crossp[((size_t)h * B + b) * H + o0 + r] = a;
        __syncthreads();
    }
}

// ---------------------------------------------------------------------------
// K5: hdn1 GEMM with virtual-fused A gather. grid (17, 4, 19), 256 threads.
// A[b,k]: k<768 lh row0 | <1536 sum crossp+out_b | <2304 aspq | <2312 LN | 0.
// W rows: n<512 va_w1 | <515 pol_w | <518 aro_w | else 0. C: [19][B][544].
// ---------------------------------------------------------------------------
__global__ __launch_bounds__(256) void hdn1_kernel(
        const float* __restrict__ lh,
        const float* __restrict__ crossp,
        const float* __restrict__ out_b,
        const float* __restrict__ aspq,
        const float* __restrict__ aro_f,
        const float* __restrict__ ln_g,
        const float* __restrict__ ln_b,
        const float* __restrict__ va_w1,
        const float* __restrict__ pol_w,
        const float* __restrict__ aro_w,
        float* __restrict__ C) {
    int z = blockIdx.z;
    int n0 = blockIdx.x * 32, m0 = blockIdx.y * 32;
    int kbase = z * KCHUNK;
    __shared__ float As[32][33];
    __shared__ float Ws[32][33];
    int t = threadIdx.x;
    int tx = t & 31, ty = t >> 5;
    int lr = t >> 3, lc = (t & 7) * 4;
    float acc[4] = {0.f, 0.f, 0.f, 0.f};
    for (int k0 = kbase; k0 < kbase + KCHUNK; k0 += 32) {
        // A gather
        {
            int bb = m0 + lr;
            int k = k0 + lc;
            float4 a;
            if (k < 768) {
                a = *(const float4*)(lh + (size_t)bb * S * H + k);
            } else if (k < 1536) {
                int c = k - 768;
                a = *(const float4*)(out_b + c);
#pragma unroll
                for (int hh = 0; hh < NH; ++hh) {
                    float4 p = *(const float4*)(crossp + ((size_t)hh * B + bb) * H + c);
                    a.x += p.x; a.y += p.y; a.z += p.z; a.w += p.w;
                }
            } else if (k < 2304) {
                a = *(const float4*)(aspq + (size_t)bb * H + (k - 1536));
            } else if (k < FUSED) {
                const float* af = aro_f + bb * 8;
                float mu = 0.f;
#pragma unroll
                for (int j = 0; j < 8; ++j) mu += af[j];
                mu *= 0.125f;
                float var = 0.f;
#pragma unroll
                for (int j = 0; j < 8; ++j) { float d = af[j] - mu; var += d * d; }
                var *= 0.125f;
                float rs = rsqrtf(var + 1e-5f);
                int c = k - 2304;
                a.x = (af[c]     - mu) * rs * ln_g[c]     + ln_b[c];
                a.y = (af[c + 1] - mu) * rs * ln_g[c + 1] + ln_b[c + 1];
                a.z = (af[c + 2] - mu) * rs * ln_g[c + 2] + ln_b[c + 2];
                a.w = (af[c + 3] - mu) * rs * ln_g[c + 3] + ln_b[c + 3];
            } else {
                a = {0.f, 0.f, 0.f, 0.f};
            }
            As[lr][lc] = a.x; As[lr][lc + 1] = a.y;
            As[lr][lc + 2] = a.z; As[lr][lc + 3] = a.w;
        }
        // W load (row-source select + k clamp vs zero-padded A)
        {
            int n = n0 + lr;
            int kk = min(k0 + lc, FUSED - 4);
            const float* wrow = va_w1 + (size_t)n * FUSED;
            bool valid = true;
            if (n >= 512) {
                if (n < 515)      wrow = pol_w + (size_t)(n - 512) * FUSED;
                else if (n < 518) wrow = aro_w + (size_t)(n - 515) * FUSED;
                else valid = false;
            }
            float4 w = {0.f, 0.f, 0.f, 0.f};
            if (valid) w = *(const float4*)(wrow + kk);
            Ws[lr][lc] = w.x; Ws[lr][lc + 1] = w.y;
            Ws[lr][lc + 2] = w.z; Ws[lr][lc + 3] = w.w;
        }
        __syncthreads();
#pragma unroll
        for (int kk = 0; kk < 32; ++kk) {
            float wv = Ws[tx][kk];
#pragma unroll
            for (int i = 0; i < 4; ++i)
                acc[i] += As[ty + 8 * i][kk] * wv;
        }
        __syncthreads();
    }
    int n = n0 + tx;
#pragma unroll
    for (int i = 0; i < 4; ++i) {
        int mm = m0 + ty + 8 * i;
        C[(size_t)z * (B * NOUT) + (size_t)mm * NOUT + n] = acc[i];
    }
}

// ---------------------------------------------------------------------------
// K6: mlp2 — reduce partials (518 cols): hs=gelu(512)+pol/aro direct;
// h2 = gelu(hs@va_w2.T+b2); va = h2@va_w3.T+b3. grid B, 512 threads.
// ---------------------------------------------------------------------------
__global__ __launch_bounds__(512) void mlp2_kernel(
        const float* __restrict__ hdn1p,
        const float* __restrict__ va_b1,
        const float* __restrict__ va_w2,
        const float* __restrict__ va_b2,
        const float* __restrict__ va_w3,
        const float* __restrict__ va_b3,
        const float* __restrict__ pol_b,
        const float* __restrict__ aro_b,
        float* __restrict__ out) {
    int b = blockIdx.x, t = threadIdx.x;
    int wave = t >> 6, lane = t & 63;
    __shared__ float hsS[512];
    __shared__ float h2S[128];
    {
        float s = 0.f;
#pragma unroll
        for (int z = 0; z < KSPLIT; ++z)
            s += hdn1p[(size_t)z * (B * NOUT) + (size_t)b * NOUT + t];
        hsS[t] = gelu(s + va_b1[t]);
    }
    if (t < 6) {
        float s = 0.f;
#pragma unroll
        for (int z = 0; z < KSPLIT; ++z)
            s += hdn1p[(size_t)z * (B * NOUT) + (size_t)b * NOUT + 512 + t];
        if (t < 3) out[256 + b * 3 + t]       = s + pol_b[t];
        else       out[640 + b * 3 + (t - 3)] = s + aro_b[t - 3];
    }
    __syncthreads();
#pragma unroll
    for (int i = 0; i < 16; ++i) {
        int n = wave * 16 + i;
        float a = 0.f;
#pragma unroll
        for (int j = 0; j < 8; ++j) {
            int k = lane + 64 * j;
            a += hsS[k] * va_w2[(size_t)n * 512 + k];
        }
        for (int off = 32; off; off >>= 1) a += __shfl_xor(a, off);
        if (lane == 0) h2S[n] = gelu(a + va_b2[n]);
    }
    __syncthreads();
    if (wave < 2) {
        float a = h2S[lane] * va_w3[wave * 128 + lane]
                + h2S[lane + 64] * va_w3[wave * 128 + lane + 64];
        for (int off = 32; off; off >>= 1) a += __shfl_xor(a, off);
        if (lane == 0) out[b * 2 + wave] = a + va_b3[wave];
    }
}

// ---------------------------------------------------------------------------
extern "C" void kernel_launch(void* const* d_in, const int* in_sizes, int n_in,
                              void* d_out, int out_size, void* d_ws, size_t ws_size,
                              hipStream_t stream) {
    const float* lh    = (const float*)d_in[0];
    const float* aro_f = (const float*)d_in[1];
    const int*   sep1  = (const int*)d_in[2];
    const int*   sep2  = (const int*)d_in[3];
    const float* in_w  = (const float*)d_in[4];
    const float* in_b  = (const float*)d_in[5];
    const float* out_w = (const float*)d_in[6];
    const float* out_b = (const float*)d_in[7];
    const float* ln_g  = (const float*)d_in[8];
    const float* ln_b  = (const float*)d_in[9];
    const float* va_w1 = (const float*)d_in[10];
    const float* va_b1 = (const float*)d_in[11];
    const float* va_w2 = (const float*)d_in[12];
    const float* va_b2 = (const float*)d_in[13];
    const float* va_w3 = (const float*)d_in[14];
    const float* va_b3 = (const float*)d_in[15];
    const float* pol_w = (const float*)d_in[16];
    const float* pol_b = (const float*)d_in[17];
    const float* aro_w = (const float*)d_in[18];
    const float* aro_b = (const float*)d_in[19];
    float* out = (float*)d_out;

    float* ws = (float*)d_ws;
    float* aspp   = ws;                              // ASL*B*H
    float* aspq   = aspp + ASL * B * H;              // B*H
    float* Ubuf   = aspq + B * H;                    // B*NH*H
    float* Opb    = Ubuf + B * NH * H;               // NSL*B*NH*H
    float* mlbuf  = Opb + (size_t)NSL * B * NH * H;  // NSL*B*NH*2
    float* crossp = mlbuf + NSL * B * NH * 2;        // NH*B*H
    float* hdn1p  = crossp + NH * B * H;             // 19*B*544

    const float* wq = in_w;
    const float* wk = in_w + H * H;
    const float* wv = in_w + 2 * H * H;
    const float* bq = in_b;
    const float* bv = in_b + 2 * H;

    // 1) asp_query partials
    aspq_part_kernel<<<dim3(B, ASL), 192, 0, stream>>>(lh, sep1, sep2, aspp);
    // 2) qu (R7): merge + q + U
    qu_kernel<<<dim3(B, NH), 256, 0, stream>>>(aspp, sep1, sep2, wq, bq, wk,
                                               aspq, Ubuf);
    // 3) flash (R7, wave-per-head)
    flash_kernel<<<dim3(B, NSL), 512, 0, stream>>>(lh, Ubuf, sep1, Opb, mlbuf);
    // 4) mergectx (R7 + cross partial per head)
    mergectx_kernel<<<dim3(B, NH), 256, 0, stream>>>(Opb, mlbuf, wv, bv,
                                                     out_w, crossp);
    // 5) hdn1 split-K GEMM with virtual-fused A (+pol/aro columns)
    hdn1_kernel<<<dim3(NOUT / 32, 4, KSPLIT), 256, 0, stream>>>(
        lh, crossp, out_b, aspq, aro_f, ln_g, ln_b,
        va_w1, pol_w, aro_w, hdn1p);
    // 6) mlp2: reduce+gelu + hdn2 + va + pol/aro writes
    mlp2_kernel<<<B, 512, 0, stream>>>(hdn1p, va_b1, va_w2, va_b2,
                                       va_w3, va_b3, pol_b, aro_b, out);
}

// Round 11
// 215.955 us; speedup vs baseline: 1.4668x; 1.2159x over previous
//
#include <hip/hip_runtime.h>
#include <hip/hip_bf16.h>
#include <math.h>

#define B 128
#define S 1024
#define H 768
#define NH 8
#define DH 96
#define FUSED 2312
#define KCHUNK 128
#define NOUT 544             // 512 hdn1 + 3 pol + 3 aro + pad
#define MD 800               // M buffer row stride (768 + bias col + pad)
#define NZ_NOCTX 13          // z in {0..5, 12..18}
#define NZ_CTX 5             // K=800 in 5 chunks of 160
#define NZTOT 18
#define ASL 8                // aspq slices
#define NSL 8                // flash slices per sample
#define FCH 16               // rows per flash chunk
#define SCALE 0.10206207261596575f  // 1/sqrt(96)
#define GELU_C 0.70710678118654752f

#define MTILES (17 * 25)     // M-GEMM tile jobs (n-tiles x d-tiles)
#define HTILES (NZ_NOCTX * 4 * 17)  // hdn1-noctx tile jobs = 884

__device__ __forceinline__ float dot4(float4 a, float4 b) {
    return a.x * b.x + a.y * b.y + a.z * b.z + a.w * b.w;
}
__device__ __forceinline__ float gelu(float x) {
    return 0.5f * x * (1.0f + erff(x * GELU_C));
}

// row pointer into the virtual [544][2312] W' (va_w1 | pol_w | aro_w | 0)
__device__ __forceinline__ const float* wrow_sel(int n, const float* va_w1,
                                                 const float* pol_w,
                                                 const float* aro_w,
                                                 bool& valid) {
    valid = true;
    if (n < 512) return va_w1 + (size_t)n * FUSED;
    if (n < 515) return pol_w + (size_t)(n - 512) * FUSED;
    if (n < 518) return aro_w + (size_t)(n - 515) * FUSED;
    valid = false;
    return va_w1;
}

// ---------------------------------------------------------------------------
// K1 hetero: bid<1024 -> aspq partial (b=bid>>3, z=bid&7, threads<192);
//            else     -> M-GEMM tile: M[n][d] = sum_c W'[n][768+c]*out_w[c][d]
//                        (+ col 768 = W'[n][768:]·out_b), 306 MFLOP.
// ---------------------------------------------------------------------------
__global__ __launch_bounds__(256) void k1_aspq_m(
        const float* __restrict__ lh,
        const int* __restrict__ sep1,
        const int* __restrict__ sep2,
        const float* __restrict__ va_w1,
        const float* __restrict__ pol_w,
        const float* __restrict__ aro_w,
        const float* __restrict__ out_w,
        const float* __restrict__ out_b,
        float* __restrict__ aspp,
        float* __restrict__ Mbuf) {
    int bid = blockIdx.x, t = threadIdx.x;
    if (bid < B * ASL) {
        if (t >= 192) return;
        int b = bid >> 3, z = bid & 7;
        int s1 = sep1[b], s2 = sep2[b];
        int lo, hi;
        if (s2 > s1 + 1) { lo = s1 + 1; hi = s2; } else { lo = 0; hi = 1; }
        const float* base = lh + ((size_t)b * S) * H + 4 * t;
        float4 a = {0.f, 0.f, 0.f, 0.f};
        for (int s = lo + z; s < hi; s += ASL) {
            float4 r = *(const float4*)(base + (size_t)s * H);
            a.x += r.x; a.y += r.y; a.z += r.z; a.w += r.w;
        }
        *(float4*)(aspp + (size_t)z * (B * H) + b * H + 4 * t) = a;
        return;
    }
    // ---- M-GEMM tile ----
    int j = bid - B * ASL;            // 0..424
    int n0 = (j / 25) * 32, d0 = (j % 25) * 32;
    __shared__ float As[32][33];
    __shared__ float Ws[32][33];
    int tx = t & 31, ty = t >> 5;
    int lr = t >> 3, lc = (t & 7) * 4;
    float acc[4] = {0.f, 0.f, 0.f, 0.f};
    for (int k0 = 0; k0 < H; k0 += 32) {
        {
            int n = n0 + lr;
            bool valid;
            const float* wr = wrow_sel(n, va_w1, pol_w, aro_w, valid);
            float4 a = {0.f, 0.f, 0.f, 0.f};
            if (valid) a = *(const float4*)(wr + H + k0 + lc);
            As[lr][lc] = a.x; As[lr][lc + 1] = a.y;
            As[lr][lc + 2] = a.z; As[lr][lc + 3] = a.w;
        }
        {
            int c = k0 + lr;
            float4 w;
            if (d0 < H) {
                w = *(const float4*)(out_w + (size_t)c * H + d0 + lc);
            } else {
                w.x = (lc == 0) ? out_b[c] : 0.f;
                w.y = 0.f; w.z = 0.f; w.w = 0.f;
            }
            Ws[lc][lr] = w.x; Ws[lc + 1][lr] = w.y;
            Ws[lc + 2][lr] = w.z; Ws[lc + 3][lr] = w.w;
        }
        __syncthreads();
#pragma unroll
        for (int kk = 0; kk < 32; ++kk) {
            float wv = Ws[tx][kk];
#pragma unroll
            for (int i = 0; i < 4; ++i)
                acc[i] += As[ty + 8 * i][kk] * wv;
        }
        __syncthreads();
    }
#pragma unroll
    for (int i = 0; i < 4; ++i)
        Mbuf[(size_t)(n0 + ty + 8 * i) * MD + d0 + tx] = acc[i];
}

// ---------------------------------------------------------------------------
// K2: qu (R7 exact) — merge aspq partials; q_h; U = q_h @ wk_h.
// grid (B, NH), 256 threads. h==0 blocks publish aspq.
// ---------------------------------------------------------------------------
__global__ void qu_kernel(const float* __restrict__ aspp,
                          const int* __restrict__ sep1,
                          const int* __restrict__ sep2,
                          const float* __restrict__ wq,
                          const float* __restrict__ bq,
                          const float* __restrict__ wk,
                          float* __restrict__ aspq,
                          float* __restrict__ U) {
    int b = blockIdx.x, h = blockIdx.y, t = threadIdx.x;
    int s1 = sep1[b], s2 = sep2[b];
    int lo, hi;
    if (s2 > s1 + 1) { lo = s1 + 1; hi = s2; } else { lo = 0; hi = 1; }
    float inv = 1.0f / (float)(hi - lo);
    __shared__ float aq[H];
    __shared__ float qh[DH];
    for (int c = t; c < H; c += 256) {
        float a = 0.f;
#pragma unroll
        for (int z = 0; z < ASL; ++z)
            a += aspp[(size_t)z * (B * H) + b * H + c];
        a *= inv;
        aq[c] = a;
        if (h == 0) aspq[b * H + c] = a;
    }
    __syncthreads();
    int wave = t >> 6, lane = t & 63;
#pragma unroll
    for (int i = 0; i < 24; ++i) {
        int d = wave * 24 + i;
        const float* wrow = wq + (size_t)(h * DH + d) * H;
        float a = 0.f;
#pragma unroll
        for (int j = 0; j < H / 64; ++j) a += wrow[lane + 64 * j] * aq[lane + 64 * j];
        for (int off = 32; off; off >>= 1) a += __shfl_xor(a, off);
        if (lane == 0) qh[d] = a + bq[h * DH + d];
    }
    __syncthreads();
    float u0 = 0.f, u1 = 0.f, u2 = 0.f;
    for (int d = 0; d < DH; ++d) {
        const float* wrow = wk + (size_t)(h * DH + d) * H;
        float qd = qh[d];
        u0 += qd * wrow[t];
        u1 += qd * wrow[t + 256];
        u2 += qd * wrow[t + 512];
    }
    float* Ub = U + ((size_t)b * NH + h) * H;
    Ub[t] = u0; Ub[t + 256] = u1; Ub[t + 512] = u2;
}

// ---------------------------------------------------------------------------
// K3 hetero: bid<1024 -> flash (R7 exact body);
//            else     -> hdn1-noctx tile (z in {0..5,12..18}): virtual A =
//                        [lh0 | (skip) | aspq | LN | 0], W' rows, partials.
// ---------------------------------------------------------------------------
__global__ __launch_bounds__(512) void k3_flash_hdn1(
        const float* __restrict__ lhg,
        const float* __restrict__ U,
        const int* __restrict__ sep1,
        const float* __restrict__ aspq,
        const float* __restrict__ aro_f,
        const float* __restrict__ ln_g,
        const float* __restrict__ ln_b,
        const float* __restrict__ va_w1,
        const float* __restrict__ pol_w,
        const float* __restrict__ aro_w,
        float* __restrict__ Op,     // [NSL][B][NH][H]
        float* __restrict__ mlb,    // [NSL][B][NH][2]
        float* __restrict__ hdn1p) {// [NZTOT][B][NOUT]
    __shared__ float smem[FCH * H];   // 48 KB (overlaid)
    int bid = blockIdx.x, t = threadIdx.x;

    if (bid < B * NSL) {
        int b = bid >> 3, z = bid & 7;
        int wave = t >> 6, lane = t & 63;
        int s1 = sep1[b];
        int tlo = (s1 > 1) ? 1 : 0;
        int thi = (s1 > 1) ? s1 : 1;
        int span = thi - tlo;
        int nrows = (span > z) ? ((span - z - 1) / NSL + 1) : 0;
        float (*lhs)[H] = (float(*)[H])smem;

        const float4* Uh = (const float4*)(U + ((size_t)b * NH + wave) * H);
        float4 u0 = Uh[lane], u1 = Uh[lane + 64], u2 = Uh[lane + 128];
        float4 O0 = {0.f, 0.f, 0.f, 0.f}, O1 = O0, O2 = O0;
        float m = -1e30f, l = 0.f;
        int rid = t >> 5, cid = t & 31;

        for (int j0 = 0; j0 < nrows; j0 += FCH) {
            int nv = min(FCH, nrows - j0);
            if (rid < nv) {
                int sg = tlo + z + NSL * (j0 + rid);
                const float4* row = (const float4*)(lhg + ((size_t)b * S + sg) * H);
                float4* dst = (float4*)lhs[rid];
#pragma unroll
                for (int k = 0; k < 6; ++k) dst[cid + 32 * k] = row[cid + 32 * k];
            }
            __syncthreads();
            for (int r = 0; r < nv; ++r) {
                const float4* xr = (const float4*)lhs[r];
                float4 x0 = xr[lane], x1 = xr[lane + 64], x2 = xr[lane + 128];
                float s = dot4(u0, x0) + dot4(u1, x1) + dot4(u2, x2);
                for (int off = 32; off; off >>= 1) s += __shfl_xor(s, off);
                s *= SCALE;
                if (s <= m) {
                    float p = __expf(s - m);
                    l += p;
                    O0.x += p * x0.x; O0.y += p * x0.y; O0.z += p * x0.z; O0.w += p * x0.w;
                    O1.x += p * x1.x; O1.y += p * x1.y; O1.z += p * x1.z; O1.w += p * x1.w;
                    O2.x += p * x2.x; O2.y += p * x2.y; O2.z += p * x2.z; O2.w += p * x2.w;
                } else {
                    float c = __expf(m - s);
                    m = s;
                    l = l * c + 1.0f;
                    O0.x = O0.x * c + x0.x; O0.y = O0.y * c + x0.y;
                    O0.z = O0.z * c + x0.z; O0.w = O0.w * c + x0.w;
                    O1.x = O1.x * c + x1.x; O1.y = O1.y * c + x1.y;
                    O1.z = O1.z * c + x1.z; O1.w = O1.w * c + x1.w;
                    O2.x = O2.x * c + x2.x; O2.y = O2.y * c + x2.y;
                    O2.z = O2.z * c + x2.z; O2.w = O2.w * c + x2.w;
                }
            }
            __syncthreads();
        }
        float4* Ob = (float4*)(Op + (((size_t)z * B + b) * NH + wave) * H);
        Ob[lane] = O0; Ob[lane + 64] = O1; Ob[lane + 128] = O2;
        if (lane == 0) {
            float* ml = mlb + ((size_t)z * B + b) * NH * 2;
            ml[2 * wave]     = m;
            ml[2 * wave + 1] = l;
        }
        return;
    }

    // ---- hdn1-noctx tile (256 active threads; all 512 hit barriers) ----
    int j = bid - B * NSL;            // 0..883
    int z13 = j / 68, rem = j % 68;
    int z = (z13 < 6) ? z13 : z13 + 6;          // {0..5, 12..18}
    int m0 = (rem / 17) * 32, n0 = (rem % 17) * 32;
    int kbase = z * KCHUNK;
    float (*As)[33] = (float(*)[33])smem;
    float (*Ws)[33] = (float(*)[33])(smem + 32 * 33);
    int tx = t & 31, ty = t >> 5;
    int lr = t >> 3, lc = (t & 7) * 4;
    float acc[4] = {0.f, 0.f, 0.f, 0.f};
    bool active = (t < 256);
    for (int k0 = kbase; k0 < kbase + KCHUNK; k0 += 32) {
        if (active) {
            int bb = m0 + lr;
            int k = k0 + lc;
            float4 a;
            if (k < 768) {
                a = *(const float4*)(lhg + (size_t)bb * S * H + k);
            } else if (k < 2304) {   // only aspq region reachable (z>=12)
                a = *(const float4*)(aspq + (size_t)bb * H + (k - 1536));
            } else if (k < FUSED) {
                const float* af = aro_f + bb * 8;
                float mu = 0.f;
#pragma unroll
                for (int jj = 0; jj < 8; ++jj) mu += af[jj];
                mu *= 0.125f;
                float var = 0.f;
#pragma unroll
                for (int jj = 0; jj < 8; ++jj) { float d = af[jj] - mu; var += d * d; }
                var *= 0.125f;
                float rs = rsqrtf(var + 1e-5f);
                int c = k - 2304;
                a.x = (af[c]     - mu) * rs * ln_g[c]     + ln_b[c];
                a.y = (af[c + 1] - mu) * rs * ln_g[c + 1] + ln_b[c + 1];
                a.z = (af[c + 2] - mu) * rs * ln_g[c + 2] + ln_b[c + 2];
                a.w = (af[c + 3] - mu) * rs * ln_g[c + 3] + ln_b[c + 3];
            } else {
                a = {0.f, 0.f, 0.f, 0.f};
            }
            As[lr][lc] = a.x; As[lr][lc + 1] = a.y;
            As[lr][lc + 2] = a.z; As[lr][lc + 3] = a.w;
            int n = n0 + lr;
            int kk = min(k0 + lc, FUSED - 4);
            bool valid;
            const float* wr = wrow_sel(n, va_w1, pol_w, aro_w, valid);
            float4 w = {0.f, 0.f, 0.f, 0.f};
            if (valid) w = *(const float4*)(wr + kk);
            Ws[lr][lc] = w.x; Ws[lr][lc + 1] = w.y;
            Ws[lr][lc + 2] = w.z; Ws[lr][lc + 3] = w.w;
        }
        __syncthreads();
        if (active) {
#pragma unroll
            for (int kk = 0; kk < 32; ++kk) {
                float wv = Ws[tx][kk];
#pragma unroll
                for (int i = 0; i < 4; ++i)
                    acc[i] += As[ty + 8 * i][kk] * wv;
            }
        }
        __syncthreads();
    }
    if (active) {
        int n = n0 + tx;
#pragma unroll
        for (int i = 0; i < 4; ++i) {
            int mm = m0 + ty + 8 * i;
            hdn1p[(size_t)z13 * (B * NOUT) + (size_t)mm * NOUT + n] = acc[i];
        }
    }
}

// ---------------------------------------------------------------------------
// K4: mergectx (R7 exact) — merge flash slices -> wsum (LDS);
// ctx_h = wv_h @ wsum + bv. grid (B, NH), 256 threads.
// ---------------------------------------------------------------------------
__global__ void mergectx_kernel(const float* __restrict__ Op,
                                const float* __restrict__ mlb,
                                const float* __restrict__ wv,
                                const float* __restrict__ bv,
                                float* __restrict__ ctx) {
    int b = blockIdx.x, h = blockIdx.y, t = threadIdx.x;
    float M = -1e30f;
#pragma unroll
    for (int z = 0; z < NSL; ++z)
        M = fmaxf(M, mlb[(((size_t)z * B + b) * NH + h) * 2]);
    float wz[NSL], L = 0.f;
#pragma unroll
    for (int z = 0; z < NSL; ++z) {
        const float* ml = mlb + (((size_t)z * B + b) * NH + h) * 2;
        float e = __expf(ml[0] - M);
        wz[z] = e;
        L += e * ml[1];
    }
    float Li = 1.0f / L;
    __shared__ float wsum[H];
    for (int c = t; c < H; c += 256) {
        float a = 0.f;
#pragma unroll
        for (int z = 0; z < NSL; ++z)
            a += wz[z] * Op[(((size_t)z * B + b) * NH + h) * H + c];
        wsum[c] = a * Li;
    }
    __syncthreads();
    int wave = t >> 6, lane = t & 63;
#pragma unroll
    for (int i = 0; i < 24; ++i) {
        int d = wave * 24 + i;
        const float* wrow = wv + (size_t)(h * DH + d) * H;
        float a = 0.f;
#pragma unroll
        for (int j = 0; j < H / 64; ++j) a += wrow[lane + 64 * j] * wsum[lane + 64 * j];
        for (int off = 32; off; off >>= 1) a += __shfl_xor(a, off);
        if (lane == 0) ctx[b * H + h * DH + d] = a + bv[h * DH + d];
    }
}

// ---------------------------------------------------------------------------
// K5: hdn1-ctx GEMM — virtual A = [ctx | 1.0 | 0] (K=800), W = Mbuf.
// grid (17, 4, 5), 256 threads. KCHUNK2 = 160.
// ---------------------------------------------------------------------------
__global__ __launch_bounds__(256) void k5_hdn1ctx(
        const float* __restrict__ ctx,
        const float* __restrict__ Mbuf,
        float* __restrict__ hdn1p) {
    int z = blockIdx.z;
    int n0 = blockIdx.x * 32, m0 = blockIdx.y * 32;
    int kbase = z * 160;
    __shared__ float As[32][33];
    __shared__ float Ws[32][33];
    int t = threadIdx.x;
    int tx = t & 31, ty = t >> 5;
    int lr = t >> 3, lc = (t & 7) * 4;
    float acc[4] = {0.f, 0.f, 0.f, 0.f};
    for (int k0 = kbase; k0 < kbase + 160; k0 += 32) {
        {
            int bb = m0 + lr;
            int k = k0 + lc;
            float4 a;
            if (k < 768)      a = *(const float4*)(ctx + (size_t)bb * H + k);
            else if (k == 768) a = {1.f, 0.f, 0.f, 0.f};
            else              a = {0.f, 0.f, 0.f, 0.f};
            As[lr][lc] = a.x; As[lr][lc + 1] = a.y;
            As[lr][lc + 2] = a.z; As[lr][lc + 3] = a.w;
        }
        {
            float4 w = *(const float4*)(Mbuf + (size_t)(n0 + lr) * MD + k0 + lc);
            Ws[lr][lc] = w.x; Ws[lr][lc + 1] = w.y;
            Ws[lr][lc + 2] = w.z; Ws[lr][lc + 3] = w.w;
        }
        __syncthreads();
#pragma unroll
        for (int kk = 0; kk < 32; ++kk) {
            float wv = Ws[tx][kk];
#pragma unroll
            for (int i = 0; i < 4; ++i)
                acc[i] += As[ty + 8 * i][kk] * wv;
        }
        __syncthreads();
    }
    int n = n0 + tx;
#pragma unroll
    for (int i = 0; i < 4; ++i) {
        int mm = m0 + ty + 8 * i;
        hdn1p[(size_t)(NZ_NOCTX + z) * (B * NOUT) + (size_t)mm * NOUT + n] = acc[i];
    }
}

// ---------------------------------------------------------------------------
// K6: mlp2 — reduce 18 partial slots: hs=gelu(512)+va_b1; pol/aro direct;
// h2 = gelu(hs@va_w2.T+b2); va = h2@va_w3.T+b3. grid B, 512 threads.
// ---------------------------------------------------------------------------
__global__ __launch_bounds__(512) void mlp2_kernel(
        const float* __restrict__ hdn1p,
        const float* __restrict__ va_b1,
        const float* __restrict__ va_w2,
        const float* __restrict__ va_b2,
        const float* __restrict__ va_w3,
        const float* __restrict__ va_b3,
        const float* __restrict__ pol_b,
        const float* __restrict__ aro_b,
        float* __restrict__ out) {
    int b = blockIdx.x, t = threadIdx.x;
    int wave = t >> 6, lane = t & 63;
    __shared__ float hsS[512];
    __shared__ float h2S[128];
    {
        float s = 0.f;
#pragma unroll
        for (int z = 0; z < NZTOT; ++z)
            s += hdn1p[(size_t)z * (B * NOUT) + (size_t)b * NOUT + t];
        hsS[t] = gelu(s + va_b1[t]);
    }
    if (t < 6) {
        float s = 0.f;
#pragma unroll
        for (int z = 0; z < NZTOT; ++z)
            s += hdn1p[(size_t)z * (B * NOUT) + (size_t)b * NOUT + 512 + t];
        if (t < 3) out[256 + b * 3 + t]       = s + pol_b[t];
        else       out[640 + b * 3 + (t - 3)] = s + aro_b[t - 3];
    }
    __syncthreads();
#pragma unroll
    for (int i = 0; i < 16; ++i) {
        int n = wave * 16 + i;
        float a = 0.f;
#pragma unroll
        for (int j = 0; j < 8; ++j) {
            int k = lane + 64 * j;
            a += hsS[k] * va_w2[(size_t)n * 512 + k];
        }
        for (int off = 32; off; off >>= 1) a += __shfl_xor(a, off);
        if (lane == 0) h2S[n] = gelu(a + va_b2[n]);
    }
    __syncthreads();
    if (wave < 2) {
        float a = h2S[lane] * va_w3[wave * 128 + lane]
                + h2S[lane + 64] * va_w3[wave * 128 + lane + 64];
        for (int off = 32; off; off >>= 1) a += __shfl_xor(a, off);
        if (lane == 0) out[b * 2 + wave] = a + va_b3[wave];
    }
}

// ---------------------------------------------------------------------------
extern "C" void kernel_launch(void* const* d_in, const int* in_sizes, int n_in,
                              void* d_out, int out_size, void* d_ws, size_t ws_size,
                              hipStream_t stream) {
    const float* lh    = (const float*)d_in[0];
    const float* aro_f = (const float*)d_in[1];
    const int*   sep1  = (const int*)d_in[2];
    const int*   sep2  = (const int*)d_in[3];
    const float* in_w  = (const float*)d_in[4];
    const float* in_b  = (const float*)d_in[5];
    const float* out_w = (const float*)d_in[6];
    const float* out_b = (const float*)d_in[7];
    const float* ln_g  = (const float*)d_in[8];
    const float* ln_b  = (const float*)d_in[9];
    const float* va_w1 = (const float*)d_in[10];
    const float* va_b1 = (const float*)d_in[11];
    const float* va_w2 = (const float*)d_in[12];
    const float* va_b2 = (const float*)d_in[13];
    const float* va_w3 = (const float*)d_in[14];
    const float* va_b3 = (const float*)d_in[15];
    const float* pol_w = (const float*)d_in[16];
    const float* pol_b = (const float*)d_in[17];
    const float* aro_w = (const float*)d_in[18];
    const float* aro_b = (const float*)d_in[19];
    float* out = (float*)d_out;

    float* ws = (float*)d_ws;
    float* aspp   = ws;                              // ASL*B*H
    float* aspq   = aspp + ASL * B * H;              // B*H
    float* Ubuf   = aspq + B * H;                    // B*NH*H
    float* Opb    = Ubuf + B * NH * H;               // NSL*B*NH*H
    float* mlbuf  = Opb + (size_t)NSL * B * NH * H;  // NSL*B*NH*2
    float* ctx    = mlbuf + NSL * B * NH * 2;        // B*H
    float* Mbuf   = ctx + B * H;                     // 544*MD
    float* hdn1p  = Mbuf + NOUT * MD;                // 18*B*NOUT

    const float* wq = in_w;
    const float* wk = in_w + H * H;
    const float* wv = in_w + 2 * H * H;
    const float* bq = in_b;
    const float* bv = in_b + 2 * H;

    // K1: aspq partials + M = W'_mid @ [out_w | out_b] (hetero)
    k1_aspq_m<<<B * ASL + MTILES, 256, 0, stream>>>(
        lh, sep1, sep2, va_w1, pol_w, aro_w, out_w, out_b, aspp, Mbuf);
    // K2: qu (R7)
    qu_kernel<<<dim3(B, NH), 256, 0, stream>>>(aspp, sep1, sep2, wq, bq, wk,
                                               aspq, Ubuf);
    // K3: flash + hdn1-noctx tiles (hetero)
    k3_flash_hdn1<<<B * NSL + HTILES, 512, 0, stream>>>(
        lh, Ubuf, sep1, aspq, aro_f, ln_g, ln_b,
        va_w1, pol_w, aro_w, Opb, mlbuf, hdn1p);
    // K4: mergectx (R7)
    mergectx_kernel<<<dim3(B, NH), 256, 0, stream>>>(Opb, mlbuf, wv, bv, ctx);
    // K5: hdn1-ctx via M (K=800, split 5)
    k5_hdn1ctx<<<dim3(17, 4, NZ_CTX), 256, 0, stream>>>(ctx, Mbuf, hdn1p);
    // K6: mlp2
    mlp2_kernel<<<B, 512, 0, stream>>>(hdn1p, va_b1, va_w2, va_b2,
                                       va_w3, va_b3, pol_b, aro_b, out);
}